// Round 3
// baseline (246.235 us; speedup 1.0000x reference)
//
#include <hip/hip_runtime.h>
#include <stdint.h>

// ---------------------------------------------------------------------------
// Attention (QKV proj + masked softmax attention + out proj), MI355X gfx950.
// bf16 MFMA with fp32 accumulate everywhere.
// attn: swapped-QK^T 32x32 flash attention, LDS-free main loop.
// ---------------------------------------------------------------------------

typedef float    f32x4  __attribute__((ext_vector_type(4)));
typedef float    f32x16 __attribute__((ext_vector_type(16)));
typedef __bf16   bf16x8 __attribute__((ext_vector_type(8)));
typedef unsigned short u16x8 __attribute__((ext_vector_type(8)));
typedef unsigned int   u32x4 __attribute__((ext_vector_type(4)));
typedef unsigned short ushort_t;
typedef unsigned int   u32;

#define HEADS 16
#define HDIM  64
#define NTOK  2048
#define BATCH 2
#define DIN   1024
#define D3    3072
#define MTOT  4096   // BATCH*NTOK

// 1/sqrt(64) * log2(e): softmax computed as exp2((s - m) * SC)
#define SC 0.18033688f

__device__ __forceinline__ ushort_t f2bf(float x) {
  uint32_t u = __builtin_bit_cast(uint32_t, x);
  uint32_t r = (u + 0x7fffu + ((u >> 16) & 1u)) >> 16;
  return (ushort_t)r;
}
__device__ __forceinline__ float bf2f(ushort_t u) {
  return __builtin_bit_cast(float, (uint32_t)u << 16);
}
__device__ __forceinline__ u32 cvt_pk_bf16(float lo, float hi) {
  u32 r;
  asm("v_cvt_pk_bf16_f32 %0, %1, %2" : "=v"(r) : "v"(lo), "v"(hi));
  return r;
}

// global->LDS direct 16B load.
__device__ __forceinline__ void gld_lds16(const void* g, void* l) {
  auto gp = reinterpret_cast<const __attribute__((address_space(1))) uint32_t*>(
      reinterpret_cast<uintptr_t>(g));
  auto lp = reinterpret_cast<__attribute__((address_space(3))) uint32_t*>(
      reinterpret_cast<uintptr_t>(l));
  __builtin_amdgcn_global_load_lds(gp, lp, 16, 0, 0);
}

// ---------------------------------------------------------------------------
// prep kernels
// ---------------------------------------------------------------------------
__global__ __launch_bounds__(256) void conv_bf16_kernel(
    const float* __restrict__ in, ushort_t* __restrict__ out, int n) {
  int i = (blockIdx.x * 256 + threadIdx.x) * 8;
  if (i >= n) return;
  float4 a = *(const float4*)(in + i);
  float4 b = *(const float4*)(in + i + 4);
  u16x8 v;
  v[0]=f2bf(a.x); v[1]=f2bf(a.y); v[2]=f2bf(a.z); v[3]=f2bf(a.w);
  v[4]=f2bf(b.x); v[5]=f2bf(b.y); v[6]=f2bf(b.z); v[7]=f2bf(b.w);
  *(u16x8*)(out + i) = v;
}

// in fp32 [R][C] -> out bf16 [C][R]   (R,C multiples of 64)
__global__ __launch_bounds__(256) void transpose_bf16_kernel(
    const float* __restrict__ in, ushort_t* __restrict__ out, int R, int C) {
  __shared__ float tile[64][65];
  const int r0 = blockIdx.y * 64, c0 = blockIdx.x * 64;
  const int t = threadIdx.x;
#pragma unroll
  for (int it = 0; it < 4; ++it) {
    int r = it * 16 + (t >> 4);
    int c = (t & 15) * 4;
    float4 v = *(const float4*)(in + (size_t)(r0 + r) * C + c0 + c);
    tile[r][c] = v.x; tile[r][c+1] = v.y; tile[r][c+2] = v.z; tile[r][c+3] = v.w;
  }
  __syncthreads();
#pragma unroll
  for (int it = 0; it < 2; ++it) {
    int idx = it * 2048 + t * 8;
    int c = idx >> 6;
    int r = idx & 63;
    u16x8 v;
#pragma unroll
    for (int j = 0; j < 8; ++j) v[j] = f2bf(tile[r + j][c]);
    *(u16x8*)(out + (size_t)(c0 + c) * R + r0 + r) = v;
  }
}

// ---------------------------------------------------------------------------
// 128x128 bf16 GEMM main loop: C = A[M][K] * Bt[N][K]^T, BK=64.
// LDS tiles [128][64] bf16, XOR-swizzled rows (byte ^= (row&7)<<4).
// ---------------------------------------------------------------------------
__device__ __forceinline__ void gemm_tile_mainloop(
    const ushort_t* __restrict__ A, const ushort_t* __restrict__ Bt,
    const int K, const int m0, const int n0,
    ushort_t* aT, ushort_t* bT, f32x4 (&acc)[4][4]) {
  const int t = threadIdx.x;
  const int l = t & 63;
  const int wr = t >> 7;
  const int wc = (t >> 6) & 1;

#pragma unroll
  for (int mi = 0; mi < 4; ++mi)
#pragma unroll
    for (int ni = 0; ni < 4; ++ni) acc[mi][ni] = f32x4{0.f, 0.f, 0.f, 0.f};

  for (int k0 = 0; k0 < K; k0 += 64) {
#pragma unroll
    for (int c = 0; c < 4; ++c) {
      const int lin = c * 4096 + t * 16;
      const int row = lin >> 7;              // 128B rows
      const int scb = (lin & 127) ^ ((row & 7) << 4);   // inverse-swizzled src col
      const int ldso = (c * 4096 + (t >> 6) * 1024) >> 1; // wave-uniform elem offset
      gld_lds16(A + (size_t)(m0 + row) * K + k0 + (scb >> 1), aT + ldso);
      gld_lds16(Bt + (size_t)(n0 + row) * K + k0 + (scb >> 1), bT + ldso);
    }
    __syncthreads();
#pragma unroll
    for (int ks = 0; ks < 2; ++ks) {
      bf16x8 af[4], bfr[4];
#pragma unroll
      for (int mi = 0; mi < 4; ++mi) {
        const int row = wr * 64 + mi * 16 + (l & 15);
        const int cb = (((l >> 4) << 4) + (ks << 6)) ^ ((row & 7) << 4);
        af[mi] = *(const bf16x8*)((const char*)aT + row * 128 + cb);
      }
#pragma unroll
      for (int ni = 0; ni < 4; ++ni) {
        const int row = wc * 64 + ni * 16 + (l & 15);
        const int cb = (((l >> 4) << 4) + (ks << 6)) ^ ((row & 7) << 4);
        bfr[ni] = *(const bf16x8*)((const char*)bT + row * 128 + cb);
      }
#pragma unroll
      for (int mi = 0; mi < 4; ++mi)
#pragma unroll
        for (int ni = 0; ni < 4; ++ni)
          acc[mi][ni] = __builtin_amdgcn_mfma_f32_16x16x32_bf16(
              af[mi], bfr[ni], acc[mi][ni], 0, 0, 0);
    }
    __syncthreads();
  }
}

// QKV GEMM: writes Q,K as [b*h][tok][d] bf16 and V transposed [b*h][d][tok].
__global__ __launch_bounds__(256) void gemm_qkv_kernel(
    const ushort_t* __restrict__ xb, const ushort_t* __restrict__ wT,
    const float* __restrict__ bias,
    ushort_t* __restrict__ Qb, ushort_t* __restrict__ Kb, ushort_t* __restrict__ Vt) {
  __shared__ __align__(16) ushort_t aT[128 * 64];
  __shared__ __align__(16) ushort_t bT[128 * 64];
  f32x4 acc[4][4];
  const int m0 = blockIdx.y * 128, n0 = blockIdx.x * 128;
  gemm_tile_mainloop(xb, wT, DIN, m0, n0, aT, bT, acc);

  const int t = threadIdx.x, l = t & 63;
  const int wr = t >> 7, wc = (t >> 6) & 1;
  const int which = n0 >> 10;  // 0=q 1=k 2=v (128-tiles never straddle)
#pragma unroll
  for (int mi = 0; mi < 4; ++mi) {
#pragma unroll
    for (int ni = 0; ni < 4; ++ni) {
      const int n = n0 + wc * 64 + ni * 16 + (l & 15);
      const int h = (n >> 6) & 15, d = n & 63;
      const float bv = bias[n];
#pragma unroll
      for (int i = 0; i < 4; ++i) {
        const int m = m0 + wr * 64 + mi * 16 + ((l >> 4) << 2) + i;
        const int b = m >> 11, tok = m & 2047;
        const ushort_t val = f2bf(acc[mi][ni][i] + bv);
        const size_t bh = (size_t)((b << 4) + h);
        if (which == 0)      Qb[(bh * NTOK + tok) * HDIM + d] = val;
        else if (which == 1) Kb[(bh * NTOK + tok) * HDIM + d] = val;
        else                 Vt[(bh * HDIM + d) * NTOK + tok] = val;
      }
    }
  }
}

// proj GEMM: fp32 out + bias
__global__ __launch_bounds__(256) void gemm_proj_kernel(
    const ushort_t* __restrict__ ab, const ushort_t* __restrict__ wT,
    const float* __restrict__ bias, float* __restrict__ out) {
  __shared__ __align__(16) ushort_t aT[128 * 64];
  __shared__ __align__(16) ushort_t bT[128 * 64];
  f32x4 acc[4][4];
  const int m0 = blockIdx.y * 128, n0 = blockIdx.x * 128;
  gemm_tile_mainloop(ab, wT, DIN, m0, n0, aT, bT, acc);

  const int t = threadIdx.x, l = t & 63;
  const int wr = t >> 7, wc = (t >> 6) & 1;
#pragma unroll
  for (int mi = 0; mi < 4; ++mi) {
#pragma unroll
    for (int ni = 0; ni < 4; ++ni) {
      const int n = n0 + wc * 64 + ni * 16 + (l & 15);
      const float bv = bias[n];
#pragma unroll
      for (int i = 0; i < 4; ++i) {
        const int m = m0 + wr * 64 + mi * 16 + ((l >> 4) << 2) + i;
        out[(size_t)m * 1024 + n] = acc[mi][ni][i] + bv;
      }
    }
  }
}

// column-mean of V over all 2048 rows, per (b,h,d): one wave per output.
__global__ __launch_bounds__(256) void vmean_kernel(
    const ushort_t* __restrict__ Vt, ushort_t* __restrict__ vmean) {
  const int row = blockIdx.x * 4 + (threadIdx.x >> 6);  // 0..2047 = bh*64+d
  const int l = threadIdx.x & 63;
  const ushort_t* src = Vt + (size_t)row * NTOK;
  float s = 0.f;
#pragma unroll
  for (int j = 0; j < 4; ++j) {
    u16x8 v = *(const u16x8*)(src + ((j << 6) + l) * 8);
#pragma unroll
    for (int k = 0; k < 8; ++k) s += bf2f(v[k]);
  }
#pragma unroll
  for (int d2 = 1; d2 < 64; d2 <<= 1) s += __shfl_xor(s, d2);
  if (l == 0) vmean[row] = f2bf(s * (1.0f / 2048.0f));
}

// ---------------------------------------------------------------------------
// flash attention, swapped-operand 32x32 MFMA, LDS-free main loop.
// Each wave owns 32 q-rows; KV tile = 64. Lane owns ONE q-row (q = lane&31):
//   St = mfma(A=K, B=Q) -> St[k][q], lane holds 16 k-values per 32-k tile
//   (k = (r&3) + 8*(r>>2) + 4*hi). Row stats: in-reg tree + 1 shfl_xor(32).
//   P->bf16 B-frags: cvt_pk + shfl_xor(32) (T12).  O^T = mfma(A=V^T, B=P)
//   -> per-lane scalar rescale/lsum. Epilogue transposes via padded LDS and
//   merges vmean rows (uniform-softmax rows) in the same coalesced store.
// ---------------------------------------------------------------------------
__global__ __launch_bounds__(256) void attn_kernel(
    const ushort_t* __restrict__ Qb, const ushort_t* __restrict__ Kb,
    const ushort_t* __restrict__ Vt, const ushort_t* __restrict__ vmean,
    const int* __restrict__ validp, ushort_t* __restrict__ ob) {
  __shared__ ushort_t ot_all[4][32 * 68];   // per-wave O tile, row stride 136B (2-way max)

  const int h = blockIdx.y, b = blockIdx.z;
  const int valid = validp[b];
  const int t = threadIdx.x, w = t >> 6, l = t & 63;
  const int lq = l & 31, hi = l >> 5;
  const int wq0 = (blockIdx.x << 7) + (w << 5);
  const size_t bh = (size_t)((b << 4) + h);
  const ushort_t* Qp = Qb + bh * (NTOK * HDIM);
  const ushort_t* Kp = Kb + bh * (NTOK * HDIM);
  const ushort_t* Vp = Vt + bh * (HDIM * NTOK);

  f32x16 oacc[2];
#pragma unroll
  for (int db = 0; db < 2; ++db)
#pragma unroll
    for (int r = 0; r < 16; ++r) oacc[db][r] = 0.f;
  float m_run = -INFINITY, lsum = 0.f;

  if (wq0 < valid) {
    // hoisted Q B-fragments: q = wq0+lq, d = ks*16 + hi*8 + j
    bf16x8 qf[4];
    const ushort_t* qbase = Qp + (size_t)(wq0 + lq) * HDIM + (hi << 3);
#pragma unroll
    for (int ks = 0; ks < 4; ++ks) qf[ks] = *(const bf16x8*)(qbase + (ks << 4));

    const int nt = (valid + 63) >> 6;
    for (int tt = 0; tt < nt; ++tt) {
      const int kv0 = tt << 6;

      // K A-fragments: k-row = kv0 + kb2*32 + lq, d = ks*16 + hi*8 + j
      bf16x8 kf[2][4];
#pragma unroll
      for (int kb2 = 0; kb2 < 2; ++kb2) {
        const ushort_t* kbase = Kp + (size_t)(kv0 + (kb2 << 5) + lq) * HDIM + (hi << 3);
#pragma unroll
        for (int ks = 0; ks < 4; ++ks) kf[kb2][ks] = *(const bf16x8*)(kbase + (ks << 4));
      }
      // V^T A-fragments: d-row = db*32 + lq, k = kv0 + kb2*32 + k2*16 + hi*8 + j
      bf16x8 vf[2][2][2];
#pragma unroll
      for (int db = 0; db < 2; ++db) {
        const ushort_t* vbase = Vp + (size_t)((db << 5) + lq) * NTOK + kv0 + (hi << 3);
#pragma unroll
        for (int kb2 = 0; kb2 < 2; ++kb2)
#pragma unroll
          for (int k2 = 0; k2 < 2; ++k2)
            vf[db][kb2][k2] = *(const bf16x8*)(vbase + (kb2 << 5) + (k2 << 4));
      }

      // S^T = K Q^T
      f32x16 st[2];
#pragma unroll
      for (int kb2 = 0; kb2 < 2; ++kb2)
#pragma unroll
        for (int r = 0; r < 16; ++r) st[kb2][r] = 0.f;
      __builtin_amdgcn_s_setprio(1);
#pragma unroll
      for (int ks = 0; ks < 4; ++ks) {
        st[0] = __builtin_amdgcn_mfma_f32_32x32x16_bf16(kf[0][ks], qf[ks], st[0], 0, 0, 0);
        st[1] = __builtin_amdgcn_mfma_f32_32x32x16_bf16(kf[1][ks], qf[ks], st[1], 0, 0, 0);
      }
      __builtin_amdgcn_s_setprio(0);

      // boundary-tile column mask
      if (kv0 + 64 > valid) {
#pragma unroll
        for (int kb2 = 0; kb2 < 2; ++kb2)
#pragma unroll
          for (int r = 0; r < 16; ++r) {
            const int k = kv0 + (kb2 << 5) + (r & 3) + ((r >> 2) << 3) + (hi << 2);
            if (k >= valid) st[kb2][r] = -1e30f;
          }
      }

      // row max (tree) + cross-half combine
      float pm;
      {
        float a8[8];
#pragma unroll
        for (int i = 0; i < 8; ++i)
          a8[i] = fmaxf(fmaxf(st[0][i], st[0][i + 8]), fmaxf(st[1][i], st[1][i + 8]));
        float b4[4];
#pragma unroll
        for (int i = 0; i < 4; ++i) b4[i] = fmaxf(a8[i], a8[i + 4]);
        pm = fmaxf(fmaxf(b4[0], b4[1]), fmaxf(b4[2], b4[3]));
      }
      pm = fmaxf(pm, __shfl_xor(pm, 32));

      // defer-max: rescale only when the running max actually grows (exact)
      if (__any(pm > m_run)) {
        const float mnew = fmaxf(m_run, pm);
        const float rs = exp2f((m_run - mnew) * SC);
        lsum *= rs;
#pragma unroll
        for (int db = 0; db < 2; ++db)
#pragma unroll
          for (int r = 0; r < 16; ++r) oacc[db][r] *= rs;
        m_run = mnew;
      }

      // P = exp2((S - m)*SC), sum, pack to bf16 B-fragments
      const float mc = m_run * SC;
      float pp[2][16];
      float ts4[4] = {0.f, 0.f, 0.f, 0.f};
#pragma unroll
      for (int kb2 = 0; kb2 < 2; ++kb2)
#pragma unroll
        for (int r = 0; r < 16; ++r) {
          const float e = exp2f(fmaf(st[kb2][r], SC, -mc));
          pp[kb2][r] = e;
          ts4[r & 3] += e;
        }
      float tsum = (ts4[0] + ts4[1]) + (ts4[2] + ts4[3]);
      tsum += __shfl_xor(tsum, 32);
      lsum += tsum;

      bf16x8 pb[2][2];
#pragma unroll
      for (int kb2 = 0; kb2 < 2; ++kb2) {
        u32 c[8];
#pragma unroll
        for (int m2 = 0; m2 < 8; ++m2)
          c[m2] = cvt_pk_bf16(pp[kb2][2 * m2], pp[kb2][2 * m2 + 1]);
        const u32 x1 = (u32)__shfl_xor((int)(hi ? c[0] : c[2]), 32);
        const u32 x2 = (u32)__shfl_xor((int)(hi ? c[1] : c[3]), 32);
        const u32 x3 = (u32)__shfl_xor((int)(hi ? c[4] : c[6]), 32);
        const u32 x4 = (u32)__shfl_xor((int)(hi ? c[5] : c[7]), 32);
        u32x4 w0, w1;
        w0[0] = hi ? x1 : c[0];  w0[1] = hi ? x2 : c[1];
        w0[2] = hi ? c[2] : x1;  w0[3] = hi ? c[3] : x2;
        w1[0] = hi ? x3 : c[4];  w1[1] = hi ? x4 : c[5];
        w1[2] = hi ? c[6] : x3;  w1[3] = hi ? c[7] : x4;
        pb[kb2][0] = __builtin_bit_cast(bf16x8, w0);
        pb[kb2][1] = __builtin_bit_cast(bf16x8, w1);
      }

      // O^T += V^T P
      __builtin_amdgcn_s_setprio(1);
#pragma unroll
      for (int db = 0; db < 2; ++db)
#pragma unroll
        for (int kb2 = 0; kb2 < 2; ++kb2)
#pragma unroll
          for (int k2 = 0; k2 < 2; ++k2)
            oacc[db] = __builtin_amdgcn_mfma_f32_32x32x16_bf16(
                vf[db][kb2][k2], pb[kb2][k2], oacc[db], 0, 0, 0);
      __builtin_amdgcn_s_setprio(0);
    }
  }

  // epilogue: normalize, transpose O^T via LDS, merge vmean rows, store.
  const float inv = (lsum > 0.f) ? 1.0f / lsum : 0.f;
  ushort_t* ot = ot_all[w];
#pragma unroll
  for (int db = 0; db < 2; ++db)
#pragma unroll
    for (int r = 0; r < 16; ++r) {
      const int d = (r & 3) + ((r >> 2) << 3) + (hi << 2) + (db << 5);
      ot[lq * 68 + d] = f2bf(oacc[db][r] * inv);
    }
  asm volatile("s_waitcnt lgkmcnt(0)" ::: "memory");
#pragma unroll
  for (int it = 0; it < 8; ++it) {
    const int c2 = it * 64 + l;        // 0..511 = 32 rows x 16 8B-chunks
    const int row = c2 >> 4;
    const int ch = c2 & 15;
    const uint2 vo = *(const uint2*)((const char*)ot + row * 136 + ch * 8);
    const uint2 vm = *(const uint2*)(vmean + (bh << 6) + ch * 4);
    const int grow = wq0 + row;
    const uint2 sel = (grow < valid) ? vo : vm;
    *(uint2*)(ob + ((size_t)(b * NTOK) + grow) * 1024 + (h << 6) + ch * 4) = sel;
  }
}

// ---------------------------------------------------------------------------
extern "C" void kernel_launch(void* const* d_in, const int* in_sizes, int n_in,
                              void* d_out, int out_size, void* d_ws, size_t ws_size,
                              hipStream_t stream) {
  (void)in_sizes; (void)n_in; (void)out_size; (void)ws_size;
  const float* x      = (const float*)d_in[0];
  const int*   validp = (const int*)d_in[1];
  const float* W_qkv  = (const float*)d_in[2];
  const float* b_qkv  = (const float*)d_in[3];
  const float* W_proj = (const float*)d_in[4];
  const float* b_proj = (const float*)d_in[5];
  float* out = (float*)d_out;

  ushort_t* xb     = (ushort_t*)d_ws;        // 4194304 elems (x bf16)
  ushort_t* wqkvT  = xb + 4194304;           // 3145728  (W_qkv^T bf16 [3072][1024])
  ushort_t* wprojT = wqkvT + 3145728;        // 1048576  (W_proj^T bf16 [1024][1024])
  ushort_t* Qb     = wprojT + 1048576;       // 4194304  ([b*h][tok][d])
  ushort_t* Kb     = Qb + 4194304;           // 4194304
  ushort_t* Vt     = Kb + 4194304;           // 4194304  ([b*h][d][tok])
  ushort_t* ab     = Vt + 4194304;           // 4194304  (attn out bf16 [m][1024])
  ushort_t* vm     = ab + 4194304;           // 2048     (vmean bf16)

  conv_bf16_kernel<<<2048, 256, 0, stream>>>(x, xb, 4194304);
  transpose_bf16_kernel<<<dim3(48, 16), 256, 0, stream>>>(W_qkv, wqkvT, 1024, 3072);
  transpose_bf16_kernel<<<dim3(16, 16), 256, 0, stream>>>(W_proj, wprojT, 1024, 1024);
  gemm_qkv_kernel<<<dim3(24, 32), 256, 0, stream>>>(xb, wqkvT, b_qkv, Qb, Kb, Vt);
  vmean_kernel<<<512, 256, 0, stream>>>(Vt, vm);
  attn_kernel<<<dim3(16, 16, 2), 256, 0, stream>>>(Qb, Kb, Vt, vm, validp, ab);
  gemm_proj_kernel<<<dim3(8, 32), 256, 0, stream>>>(ab, wprojT, b_proj, out);
}

// Round 4
// 224.985 us; speedup vs baseline: 1.0945x; 1.0945x over previous
//
#include <hip/hip_runtime.h>
#include <stdint.h>

// ---------------------------------------------------------------------------
// Attention (QKV proj + masked softmax attention + out proj), MI355X gfx950.
// bf16 MFMA with fp32 accumulate everywhere.
// attn: swapped-QK^T 32x32 flash attention; K/V staged in LDS per block
// (2-phase pipeline), softmax fully in-register.
// ---------------------------------------------------------------------------

typedef float    f32x4  __attribute__((ext_vector_type(4)));
typedef float    f32x16 __attribute__((ext_vector_type(16)));
typedef __bf16   bf16x8 __attribute__((ext_vector_type(8)));
typedef unsigned short u16x8 __attribute__((ext_vector_type(8)));
typedef unsigned int   u32x4 __attribute__((ext_vector_type(4)));
typedef unsigned short ushort_t;
typedef unsigned int   u32;

#define HEADS 16
#define HDIM  64
#define NTOK  2048
#define BATCH 2
#define DIN   1024
#define D3    3072
#define MTOT  4096   // BATCH*NTOK

// 1/sqrt(64) * log2(e): softmax computed as exp2((s - m) * SC)
#define SC 0.18033688f

__device__ __forceinline__ ushort_t f2bf(float x) {
  uint32_t u = __builtin_bit_cast(uint32_t, x);
  uint32_t r = (u + 0x7fffu + ((u >> 16) & 1u)) >> 16;
  return (ushort_t)r;
}
__device__ __forceinline__ float bf2f(ushort_t u) {
  return __builtin_bit_cast(float, (uint32_t)u << 16);
}
__device__ __forceinline__ u32 cvt_pk_bf16(float lo, float hi) {
  u32 r;
  asm("v_cvt_pk_bf16_f32 %0, %1, %2" : "=v"(r) : "v"(lo), "v"(hi));
  return r;
}

// global->LDS direct 16B load.
__device__ __forceinline__ void gld_lds16(const void* g, void* l) {
  auto gp = reinterpret_cast<const __attribute__((address_space(1))) uint32_t*>(
      reinterpret_cast<uintptr_t>(g));
  auto lp = reinterpret_cast<__attribute__((address_space(3))) uint32_t*>(
      reinterpret_cast<uintptr_t>(l));
  __builtin_amdgcn_global_load_lds(gp, lp, 16, 0, 0);
}

// ---------------------------------------------------------------------------
// prep kernels
// ---------------------------------------------------------------------------
__global__ __launch_bounds__(256) void conv_bf16_kernel(
    const float* __restrict__ in, ushort_t* __restrict__ out, int n) {
  int i = (blockIdx.x * 256 + threadIdx.x) * 8;
  if (i >= n) return;
  float4 a = *(const float4*)(in + i);
  float4 b = *(const float4*)(in + i + 4);
  u16x8 v;
  v[0]=f2bf(a.x); v[1]=f2bf(a.y); v[2]=f2bf(a.z); v[3]=f2bf(a.w);
  v[4]=f2bf(b.x); v[5]=f2bf(b.y); v[6]=f2bf(b.z); v[7]=f2bf(b.w);
  *(u16x8*)(out + i) = v;
}

// in fp32 [R][C] -> out bf16 [C][R]   (R,C multiples of 64)
__global__ __launch_bounds__(256) void transpose_bf16_kernel(
    const float* __restrict__ in, ushort_t* __restrict__ out, int R, int C) {
  __shared__ float tile[64][65];
  const int r0 = blockIdx.y * 64, c0 = blockIdx.x * 64;
  const int t = threadIdx.x;
#pragma unroll
  for (int it = 0; it < 4; ++it) {
    int r = it * 16 + (t >> 4);
    int c = (t & 15) * 4;
    float4 v = *(const float4*)(in + (size_t)(r0 + r) * C + c0 + c);
    tile[r][c] = v.x; tile[r][c+1] = v.y; tile[r][c+2] = v.z; tile[r][c+3] = v.w;
  }
  __syncthreads();
#pragma unroll
  for (int it = 0; it < 2; ++it) {
    int idx = it * 2048 + t * 8;
    int c = idx >> 6;
    int r = idx & 63;
    u16x8 v;
#pragma unroll
    for (int j = 0; j < 8; ++j) v[j] = f2bf(tile[r + j][c]);
    *(u16x8*)(out + (size_t)(c0 + c) * R + r0 + r) = v;
  }
}

// ---------------------------------------------------------------------------
// 128x128 bf16 GEMM main loop: C = A[M][K] * Bt[N][K]^T, BK=64.
// LDS tiles [128][64] bf16, XOR-swizzled rows (byte ^= (row&7)<<4).
// ---------------------------------------------------------------------------
__device__ __forceinline__ void gemm_tile_mainloop(
    const ushort_t* __restrict__ A, const ushort_t* __restrict__ Bt,
    const int K, const int m0, const int n0,
    ushort_t* aT, ushort_t* bT, f32x4 (&acc)[4][4]) {
  const int t = threadIdx.x;
  const int l = t & 63;
  const int wr = t >> 7;
  const int wc = (t >> 6) & 1;

#pragma unroll
  for (int mi = 0; mi < 4; ++mi)
#pragma unroll
    for (int ni = 0; ni < 4; ++ni) acc[mi][ni] = f32x4{0.f, 0.f, 0.f, 0.f};

  for (int k0 = 0; k0 < K; k0 += 64) {
#pragma unroll
    for (int c = 0; c < 4; ++c) {
      const int lin = c * 4096 + t * 16;
      const int row = lin >> 7;              // 128B rows
      const int scb = (lin & 127) ^ ((row & 7) << 4);   // inverse-swizzled src col
      const int ldso = (c * 4096 + (t >> 6) * 1024) >> 1; // wave-uniform elem offset
      gld_lds16(A + (size_t)(m0 + row) * K + k0 + (scb >> 1), aT + ldso);
      gld_lds16(Bt + (size_t)(n0 + row) * K + k0 + (scb >> 1), bT + ldso);
    }
    __syncthreads();
#pragma unroll
    for (int ks = 0; ks < 2; ++ks) {
      bf16x8 af[4], bfr[4];
#pragma unroll
      for (int mi = 0; mi < 4; ++mi) {
        const int row = wr * 64 + mi * 16 + (l & 15);
        const int cb = (((l >> 4) << 4) + (ks << 6)) ^ ((row & 7) << 4);
        af[mi] = *(const bf16x8*)((const char*)aT + row * 128 + cb);
      }
#pragma unroll
      for (int ni = 0; ni < 4; ++ni) {
        const int row = wc * 64 + ni * 16 + (l & 15);
        const int cb = (((l >> 4) << 4) + (ks << 6)) ^ ((row & 7) << 4);
        bfr[ni] = *(const bf16x8*)((const char*)bT + row * 128 + cb);
      }
#pragma unroll
      for (int mi = 0; mi < 4; ++mi)
#pragma unroll
        for (int ni = 0; ni < 4; ++ni)
          acc[mi][ni] = __builtin_amdgcn_mfma_f32_16x16x32_bf16(
              af[mi], bfr[ni], acc[mi][ni], 0, 0, 0);
    }
    __syncthreads();
  }
}

// QKV GEMM: writes Q,K as [b*h][tok][d] bf16 and V transposed [b*h][d][tok].
__global__ __launch_bounds__(256) void gemm_qkv_kernel(
    const ushort_t* __restrict__ xb, const ushort_t* __restrict__ wT,
    const float* __restrict__ bias,
    ushort_t* __restrict__ Qb, ushort_t* __restrict__ Kb, ushort_t* __restrict__ Vt) {
  __shared__ __align__(16) ushort_t aT[128 * 64];
  __shared__ __align__(16) ushort_t bT[128 * 64];
  f32x4 acc[4][4];
  const int m0 = blockIdx.y * 128, n0 = blockIdx.x * 128;
  gemm_tile_mainloop(xb, wT, DIN, m0, n0, aT, bT, acc);

  const int t = threadIdx.x, l = t & 63;
  const int wr = t >> 7, wc = (t >> 6) & 1;
  const int which = n0 >> 10;  // 0=q 1=k 2=v (128-tiles never straddle)
#pragma unroll
  for (int mi = 0; mi < 4; ++mi) {
#pragma unroll
    for (int ni = 0; ni < 4; ++ni) {
      const int n = n0 + wc * 64 + ni * 16 + (l & 15);
      const int h = (n >> 6) & 15, d = n & 63;
      const float bv = bias[n];
#pragma unroll
      for (int i = 0; i < 4; ++i) {
        const int m = m0 + wr * 64 + mi * 16 + ((l >> 4) << 2) + i;
        const int b = m >> 11, tok = m & 2047;
        const ushort_t val = f2bf(acc[mi][ni][i] + bv);
        const size_t bh = (size_t)((b << 4) + h);
        if (which == 0)      Qb[(bh * NTOK + tok) * HDIM + d] = val;
        else if (which == 1) Kb[(bh * NTOK + tok) * HDIM + d] = val;
        else                 Vt[(bh * HDIM + d) * NTOK + tok] = val;
      }
    }
  }
}

// proj GEMM: fp32 out + bias
__global__ __launch_bounds__(256) void gemm_proj_kernel(
    const ushort_t* __restrict__ ab, const ushort_t* __restrict__ wT,
    const float* __restrict__ bias, float* __restrict__ out) {
  __shared__ __align__(16) ushort_t aT[128 * 64];
  __shared__ __align__(16) ushort_t bT[128 * 64];
  f32x4 acc[4][4];
  const int m0 = blockIdx.y * 128, n0 = blockIdx.x * 128;
  gemm_tile_mainloop(ab, wT, DIN, m0, n0, aT, bT, acc);

  const int t = threadIdx.x, l = t & 63;
  const int wr = t >> 7, wc = (t >> 6) & 1;
#pragma unroll
  for (int mi = 0; mi < 4; ++mi) {
#pragma unroll
    for (int ni = 0; ni < 4; ++ni) {
      const int n = n0 + wc * 64 + ni * 16 + (l & 15);
      const float bv = bias[n];
#pragma unroll
      for (int i = 0; i < 4; ++i) {
        const int m = m0 + wr * 64 + mi * 16 + ((l >> 4) << 2) + i;
        out[(size_t)m * 1024 + n] = acc[mi][ni][i] + bv;
      }
    }
  }
}

// column-mean of V over all 2048 rows, per (b,h,d): one wave per output.
__global__ __launch_bounds__(256) void vmean_kernel(
    const ushort_t* __restrict__ Vt, ushort_t* __restrict__ vmean) {
  const int row = blockIdx.x * 4 + (threadIdx.x >> 6);  // 0..2047 = bh*64+d
  const int l = threadIdx.x & 63;
  const ushort_t* src = Vt + (size_t)row * NTOK;
  float s = 0.f;
#pragma unroll
  for (int j = 0; j < 4; ++j) {
    u16x8 v = *(const u16x8*)(src + ((j << 6) + l) * 8);
#pragma unroll
    for (int k = 0; k < 8; ++k) s += bf2f(v[k]);
  }
#pragma unroll
  for (int d2 = 1; d2 < 64; d2 <<= 1) s += __shfl_xor(s, d2);
  if (l == 0) vmean[row] = f2bf(s * (1.0f / 2048.0f));
}

// ---------------------------------------------------------------------------
// flash attention, swapped-operand 32x32 MFMA.
// Block = 4 waves x 32 q-rows = 128 q. KV tile = 64, staged in LDS per BLOCK
// (shared by all 4 waves; was per-wave global loads -> 8x fewer L1 lines),
// double-buffered 2-phase pipeline: issue STAGE(t+1), compute(t), barrier.
// Lane owns ONE q-row (q = lane&31):
//   St = mfma(A=K, B=Q) -> St[k][q]; row stats in-reg tree + 1 shfl_xor(32).
//   P->bf16 B-frags: cvt_pk + shfl_xor(32).  O^T = mfma(A=V^T, B=P).
// Epilogue transposes O^T via LDS (overlaying the staging buffers) and
// merges vmean rows (uniform-softmax rows) in the same coalesced store.
// ---------------------------------------------------------------------------
__global__ __launch_bounds__(256) void attn_kernel(
    const ushort_t* __restrict__ Qb, const ushort_t* __restrict__ Kb,
    const ushort_t* __restrict__ Vt, const ushort_t* __restrict__ vmean,
    const int* __restrict__ validp, ushort_t* __restrict__ ob) {
  // buf p: K tile [64][64] at p*16384, V^T tile [64][64] at p*16384+8192.
  // epilogue ot (4 waves x 32x68 ushort = 17408B) overlays the same memory.
  __shared__ __align__(16) char smem_raw[32768];

  const int h = blockIdx.y, b = blockIdx.z;
  const int valid = validp[b];
  const int t = threadIdx.x, w = t >> 6, l = t & 63;
  const int lq = l & 31, hi = l >> 5;
  const int bq0 = blockIdx.x << 7;
  const int wq0 = bq0 + (w << 5);
  const size_t bh = (size_t)((b << 4) + h);
  const ushort_t* Qp = Qb + bh * (NTOK * HDIM);
  const ushort_t* Kp = Kb + bh * (NTOK * HDIM);
  const ushort_t* Vp = Vt + bh * (HDIM * NTOK);

  f32x16 oacc[2];
#pragma unroll
  for (int db = 0; db < 2; ++db)
#pragma unroll
    for (int r = 0; r < 16; ++r) oacc[db][r] = 0.f;
  float m_run = -INFINITY, lsum = 0.f;

  if (bq0 < valid) {
    const bool qvalid = (wq0 < valid);
    // hoisted Q B-fragments: q = wq0+lq, d = ks*16 + hi*8 + j
    bf16x8 qf[4];
    if (qvalid) {
      const ushort_t* qbase = Qp + (size_t)(wq0 + lq) * HDIM + (hi << 3);
#pragma unroll
      for (int ks = 0; ks < 4; ++ks) qf[ks] = *(const bf16x8*)(qbase + (ks << 4));
    }

    const int nt = (valid + 63) >> 6;

    // stage KV tile tt into buffer p (all 256 threads; coalesced gld_lds)
    auto STAGE = [&](int p, int kv0) {
      char* kdst = smem_raw + p * 16384;
      char* vdst = kdst + 8192;
#pragma unroll
      for (int c = 0; c < 2; ++c) {
        const int lin = c * 4096 + t * 16;
        const int row = lin >> 7;                        // 128B rows
        const int scb = (lin & 127) ^ ((row & 7) << 4);  // inverse-swizzle src
        const int ldso = c * 4096 + (w << 10);           // wave-uniform byte off
        // K tile: rows = consecutive tokens -> 8KB contiguous in global
        gld_lds16(Kp + (size_t)(kv0 + row) * HDIM + (scb >> 1), kdst + ldso);
        // V^T tile: row = d (stride NTOK), cols = kv window
        gld_lds16(Vp + (size_t)row * NTOK + kv0 + (scb >> 1), vdst + ldso);
      }
    };

    STAGE(0, 0);
    __syncthreads();

    for (int tt = 0; tt < nt; ++tt) {
      const int p = tt & 1;
      const int kv0 = tt << 6;
      if (tt + 1 < nt) STAGE(p ^ 1, (tt + 1) << 6);

      if (qvalid) {
        const char* kbuf = smem_raw + p * 16384;
        const char* vbuf = kbuf + 8192;

        // K A-fragments from LDS: k-row = kb2*32+lq, elem col = ks*16+hi*8
        bf16x8 kf[2][4];
#pragma unroll
        for (int kb2 = 0; kb2 < 2; ++kb2) {
          const int row = (kb2 << 5) + lq;
          const int sw = (row & 7) << 4;
#pragma unroll
          for (int ks = 0; ks < 4; ++ks)
            kf[kb2][ks] = *(const bf16x8*)(kbuf + row * 128 + (((ks << 5) + (hi << 4)) ^ sw));
        }

        // S^T = K Q^T
        f32x16 st[2];
#pragma unroll
        for (int kb2 = 0; kb2 < 2; ++kb2)
#pragma unroll
          for (int r = 0; r < 16; ++r) st[kb2][r] = 0.f;
        __builtin_amdgcn_s_setprio(1);
#pragma unroll
        for (int ks = 0; ks < 4; ++ks) {
          st[0] = __builtin_amdgcn_mfma_f32_32x32x16_bf16(kf[0][ks], qf[ks], st[0], 0, 0, 0);
          st[1] = __builtin_amdgcn_mfma_f32_32x32x16_bf16(kf[1][ks], qf[ks], st[1], 0, 0, 0);
        }
        __builtin_amdgcn_s_setprio(0);

        // boundary-tile column mask
        if (kv0 + 64 > valid) {
#pragma unroll
          for (int kb2 = 0; kb2 < 2; ++kb2)
#pragma unroll
            for (int r = 0; r < 16; ++r) {
              const int k = kv0 + (kb2 << 5) + (r & 3) + ((r >> 2) << 3) + (hi << 2);
              if (k >= valid) st[kb2][r] = -1e30f;
            }
        }

        // row max (tree) + cross-half combine
        float pm;
        {
          float a8[8];
#pragma unroll
          for (int i = 0; i < 8; ++i)
            a8[i] = fmaxf(fmaxf(st[0][i], st[0][i + 8]), fmaxf(st[1][i], st[1][i + 8]));
          float b4[4];
#pragma unroll
          for (int i = 0; i < 4; ++i) b4[i] = fmaxf(a8[i], a8[i + 4]);
          pm = fmaxf(fmaxf(b4[0], b4[1]), fmaxf(b4[2], b4[3]));
        }
        pm = fmaxf(pm, __shfl_xor(pm, 32));

        // defer-max: rescale only when the running max actually grows (exact)
        if (__any(pm > m_run)) {
          const float mnew = fmaxf(m_run, pm);
          const float rs = exp2f((m_run - mnew) * SC);
          lsum *= rs;
#pragma unroll
          for (int db = 0; db < 2; ++db)
#pragma unroll
            for (int r = 0; r < 16; ++r) oacc[db][r] *= rs;
          m_run = mnew;
        }

        // P = exp2((S - m)*SC), sum
        const float mc = m_run * SC;
        float pp[2][16];
        float ts4[4] = {0.f, 0.f, 0.f, 0.f};
#pragma unroll
        for (int kb2 = 0; kb2 < 2; ++kb2)
#pragma unroll
          for (int r = 0; r < 16; ++r) {
            const float e = exp2f(fmaf(st[kb2][r], SC, -mc));
            pp[kb2][r] = e;
            ts4[r & 3] += e;
          }
        float tsum = (ts4[0] + ts4[1]) + (ts4[2] + ts4[3]);
        tsum += __shfl_xor(tsum, 32);
        lsum += tsum;

        // V^T A-fragments from LDS: d-row = db*32+lq, elem col = ks2*16+hi*8
        bf16x8 vf[2][4];
#pragma unroll
        for (int db = 0; db < 2; ++db) {
          const int row = (db << 5) + lq;
          const int sw = (row & 7) << 4;
#pragma unroll
          for (int ks2 = 0; ks2 < 4; ++ks2)
            vf[db][ks2] = *(const bf16x8*)(vbuf + row * 128 + (((ks2 << 5) + (hi << 4)) ^ sw));
        }

        // pack P to bf16 B-fragments (cvt_pk + cross-half shfl)
        bf16x8 pb[2][2];
#pragma unroll
        for (int kb2 = 0; kb2 < 2; ++kb2) {
          u32 c[8];
#pragma unroll
          for (int m2 = 0; m2 < 8; ++m2)
            c[m2] = cvt_pk_bf16(pp[kb2][2 * m2], pp[kb2][2 * m2 + 1]);
          const u32 x1 = (u32)__shfl_xor((int)(hi ? c[0] : c[2]), 32);
          const u32 x2 = (u32)__shfl_xor((int)(hi ? c[1] : c[3]), 32);
          const u32 x3 = (u32)__shfl_xor((int)(hi ? c[4] : c[6]), 32);
          const u32 x4 = (u32)__shfl_xor((int)(hi ? c[5] : c[7]), 32);
          u32x4 w0, w1;
          w0[0] = hi ? x1 : c[0];  w0[1] = hi ? x2 : c[1];
          w0[2] = hi ? c[2] : x1;  w0[3] = hi ? c[3] : x2;
          w1[0] = hi ? x3 : c[4];  w1[1] = hi ? x4 : c[5];
          w1[2] = hi ? c[6] : x3;  w1[3] = hi ? c[7] : x4;
          pb[kb2][0] = __builtin_bit_cast(bf16x8, w0);
          pb[kb2][1] = __builtin_bit_cast(bf16x8, w1);
        }

        // O^T += V^T P
        __builtin_amdgcn_s_setprio(1);
#pragma unroll
        for (int db = 0; db < 2; ++db)
#pragma unroll
          for (int kb2 = 0; kb2 < 2; ++kb2)
#pragma unroll
            for (int k2 = 0; k2 < 2; ++k2)
              oacc[db] = __builtin_amdgcn_mfma_f32_32x32x16_bf16(
                  vf[db][(kb2 << 1) + k2], pb[kb2][k2], oacc[db], 0, 0, 0);
        __builtin_amdgcn_s_setprio(0);
      }

      __syncthreads();   // drains STAGE vmcnt + protects both buffers
    }
  }

  // epilogue: normalize, transpose O^T via LDS (overlay), merge vmean, store.
  const float inv = (lsum > 0.f) ? 1.0f / lsum : 0.f;
  ushort_t* ot = (ushort_t*)smem_raw + w * (32 * 68);
#pragma unroll
  for (int db = 0; db < 2; ++db)
#pragma unroll
    for (int r = 0; r < 16; ++r) {
      const int d = (r & 3) + ((r >> 2) << 3) + (hi << 2) + (db << 5);
      ot[lq * 68 + d] = f2bf(oacc[db][r] * inv);
    }
  asm volatile("s_waitcnt lgkmcnt(0)" ::: "memory");
#pragma unroll
  for (int it = 0; it < 8; ++it) {
    const int c2 = it * 64 + l;        // 0..511 = 32 rows x 16 8B-chunks
    const int row = c2 >> 4;
    const int ch = c2 & 15;
    const uint2 vo = *(const uint2*)((const char*)ot + row * 136 + ch * 8);
    const uint2 vm = *(const uint2*)(vmean + (bh << 6) + ch * 4);
    const int grow = (blockIdx.x << 7) + (w << 5) + row;
    const uint2 sel = (grow < valid) ? vo : vm;
    *(uint2*)(ob + ((size_t)(b * NTOK) + grow) * 1024 + (h << 6) + ch * 4) = sel;
  }
}

// ---------------------------------------------------------------------------
extern "C" void kernel_launch(void* const* d_in, const int* in_sizes, int n_in,
                              void* d_out, int out_size, void* d_ws, size_t ws_size,
                              hipStream_t stream) {
  (void)in_sizes; (void)n_in; (void)out_size; (void)ws_size;
  const float* x      = (const float*)d_in[0];
  const int*   validp = (const int*)d_in[1];
  const float* W_qkv  = (const float*)d_in[2];
  const float* b_qkv  = (const float*)d_in[3];
  const float* W_proj = (const float*)d_in[4];
  const float* b_proj = (const float*)d_in[5];
  float* out = (float*)d_out;

  ushort_t* xb     = (ushort_t*)d_ws;        // 4194304 elems (x bf16)
  ushort_t* wqkvT  = xb + 4194304;           // 3145728  (W_qkv^T bf16 [3072][1024])
  ushort_t* wprojT = wqkvT + 3145728;        // 1048576  (W_proj^T bf16 [1024][1024])
  ushort_t* Qb     = wprojT + 1048576;       // 4194304  ([b*h][tok][d])
  ushort_t* Kb     = Qb + 4194304;           // 4194304
  ushort_t* Vt     = Kb + 4194304;           // 4194304  ([b*h][d][tok])
  ushort_t* ab     = Vt + 4194304;           // 4194304  (attn out bf16 [m][1024])
  ushort_t* vm     = ab + 4194304;           // 2048     (vmean bf16)

  conv_bf16_kernel<<<2048, 256, 0, stream>>>(x, xb, 4194304);
  transpose_bf16_kernel<<<dim3(48, 16), 256, 0, stream>>>(W_qkv, wqkvT, 1024, 3072);
  transpose_bf16_kernel<<<dim3(16, 16), 256, 0, stream>>>(W_proj, wprojT, 1024, 1024);
  gemm_qkv_kernel<<<dim3(24, 32), 256, 0, stream>>>(xb, wqkvT, b_qkv, Qb, Kb, Vt);
  vmean_kernel<<<512, 256, 0, stream>>>(Vt, vm);
  attn_kernel<<<dim3(16, 16, 2), 256, 0, stream>>>(Qb, Kb, Vt, vm, validp, ab);
  gemm_proj_kernel<<<dim3(8, 32), 256, 0, stream>>>(ab, wprojT, b_proj, out);
}

// Round 5
// 206.589 us; speedup vs baseline: 1.1919x; 1.0890x over previous
//
#include <hip/hip_runtime.h>
#include <stdint.h>

// ---------------------------------------------------------------------------
// Attention (QKV proj + masked softmax attention + out proj), MI355X gfx950.
// bf16 MFMA with fp32 accumulate everywhere.
// attn: swapped-QK^T 32x32 flash attention; K/V staged in LDS per block.
// gemm_qkv: V-blocks compute C^T via swapped MFMA operands -> coalesced Vt.
// prep: conv + both weight transposes fused (grid-partitioned).
// ---------------------------------------------------------------------------

typedef float    f32x4  __attribute__((ext_vector_type(4)));
typedef float    f32x16 __attribute__((ext_vector_type(16)));
typedef __bf16   bf16x8 __attribute__((ext_vector_type(8)));
typedef unsigned short u16x8 __attribute__((ext_vector_type(8)));
typedef unsigned int   u32x4 __attribute__((ext_vector_type(4)));
typedef unsigned short ushort_t;
typedef unsigned int   u32;

#define HEADS 16
#define HDIM  64
#define NTOK  2048
#define BATCH 2
#define DIN   1024
#define D3    3072
#define MTOT  4096   // BATCH*NTOK

// 1/sqrt(64) * log2(e): softmax computed as exp2((s - m) * SC)
#define SC 0.18033688f

__device__ __forceinline__ ushort_t f2bf(float x) {
  uint32_t u = __builtin_bit_cast(uint32_t, x);
  uint32_t r = (u + 0x7fffu + ((u >> 16) & 1u)) >> 16;
  return (ushort_t)r;
}
__device__ __forceinline__ float bf2f(ushort_t u) {
  return __builtin_bit_cast(float, (uint32_t)u << 16);
}
__device__ __forceinline__ u32 cvt_pk_bf16(float lo, float hi) {
  u32 r;
  asm("v_cvt_pk_bf16_f32 %0, %1, %2" : "=v"(r) : "v"(lo), "v"(hi));
  return r;
}

// global->LDS direct 16B load.
__device__ __forceinline__ void gld_lds16(const void* g, void* l) {
  auto gp = reinterpret_cast<const __attribute__((address_space(1))) uint32_t*>(
      reinterpret_cast<uintptr_t>(g));
  auto lp = reinterpret_cast<__attribute__((address_space(3))) uint32_t*>(
      reinterpret_cast<uintptr_t>(l));
  __builtin_amdgcn_global_load_lds(gp, lp, 16, 0, 0);
}

// ---------------------------------------------------------------------------
// fused prep: blocks [0,2048) convert x -> bf16; [2048,2816) transpose W_qkv;
// [2816,3072) transpose W_proj.  (3 launches -> 1)
// ---------------------------------------------------------------------------
__device__ __forceinline__ void transpose_tile(
    const float* __restrict__ in, ushort_t* __restrict__ out,
    int R, int C, int bx, int by, float (*tile)[65]) {
  const int r0 = by * 64, c0 = bx * 64;
  const int t = threadIdx.x;
#pragma unroll
  for (int it = 0; it < 4; ++it) {
    int r = it * 16 + (t >> 4);
    int c = (t & 15) * 4;
    float4 v = *(const float4*)(in + (size_t)(r0 + r) * C + c0 + c);
    tile[r][c] = v.x; tile[r][c+1] = v.y; tile[r][c+2] = v.z; tile[r][c+3] = v.w;
  }
  __syncthreads();
#pragma unroll
  for (int it = 0; it < 2; ++it) {
    int idx = it * 2048 + t * 8;
    int c = idx >> 6;
    int r = idx & 63;
    u16x8 v;
#pragma unroll
    for (int j = 0; j < 8; ++j) v[j] = f2bf(tile[r + j][c]);
    *(u16x8*)(out + (size_t)(c0 + c) * R + r0 + r) = v;
  }
}

__global__ __launch_bounds__(256) void prep_kernel(
    const float* __restrict__ x, ushort_t* __restrict__ xb,
    const float* __restrict__ Wq, ushort_t* __restrict__ wqT,
    const float* __restrict__ Wp, ushort_t* __restrict__ wpT) {
  __shared__ float tile[64][65];
  const int bid = blockIdx.x;
  if (bid < 2048) {
    const int i = (bid * 256 + threadIdx.x) * 8;
    float4 a = *(const float4*)(x + i);
    float4 b = *(const float4*)(x + i + 4);
    u16x8 v;
    v[0]=f2bf(a.x); v[1]=f2bf(a.y); v[2]=f2bf(a.z); v[3]=f2bf(a.w);
    v[4]=f2bf(b.x); v[5]=f2bf(b.y); v[6]=f2bf(b.z); v[7]=f2bf(b.w);
    *(u16x8*)(xb + i) = v;
  } else if (bid < 2816) {
    const int idx = bid - 2048;                 // 48 x 16 tiles
    transpose_tile(Wq, wqT, 1024, 3072, idx % 48, idx / 48, tile);
  } else {
    const int idx = bid - 2816;                 // 16 x 16 tiles
    transpose_tile(Wp, wpT, 1024, 1024, idx % 16, idx / 16, tile);
  }
}

// ---------------------------------------------------------------------------
// 128x128 bf16 GEMM main loop: C = A[M][K] * Bt[N][K]^T, BK=64.
// LDS tiles [128][64] bf16, XOR-swizzled rows (byte ^= (row&7)<<4).
// SWAP=true computes C^T (operands exchanged; identical cost) so the
// epilogue's lane layout has col=m, row=n -> used for transposed V stores.
// ---------------------------------------------------------------------------
template <bool SWAP>
__device__ __forceinline__ void gemm_tile_mainloop(
    const ushort_t* __restrict__ A, const ushort_t* __restrict__ Bt,
    const int K, const int m0, const int n0,
    ushort_t* aT, ushort_t* bT, f32x4 (&acc)[4][4]) {
  const int t = threadIdx.x;
  const int l = t & 63;
  const int wr = t >> 7;
  const int wc = (t >> 6) & 1;

#pragma unroll
  for (int mi = 0; mi < 4; ++mi)
#pragma unroll
    for (int ni = 0; ni < 4; ++ni) acc[mi][ni] = f32x4{0.f, 0.f, 0.f, 0.f};

  for (int k0 = 0; k0 < K; k0 += 64) {
#pragma unroll
    for (int c = 0; c < 4; ++c) {
      const int lin = c * 4096 + t * 16;
      const int row = lin >> 7;              // 128B rows
      const int scb = (lin & 127) ^ ((row & 7) << 4);   // inverse-swizzled src col
      const int ldso = (c * 4096 + (t >> 6) * 1024) >> 1; // wave-uniform elem offset
      gld_lds16(A + (size_t)(m0 + row) * K + k0 + (scb >> 1), aT + ldso);
      gld_lds16(Bt + (size_t)(n0 + row) * K + k0 + (scb >> 1), bT + ldso);
    }
    __syncthreads();
#pragma unroll
    for (int ks = 0; ks < 2; ++ks) {
      bf16x8 af[4], bfr[4];
#pragma unroll
      for (int mi = 0; mi < 4; ++mi) {
        const int row = wr * 64 + mi * 16 + (l & 15);
        const int cb = (((l >> 4) << 4) + (ks << 6)) ^ ((row & 7) << 4);
        af[mi] = *(const bf16x8*)((const char*)aT + row * 128 + cb);
      }
#pragma unroll
      for (int ni = 0; ni < 4; ++ni) {
        const int row = wc * 64 + ni * 16 + (l & 15);
        const int cb = (((l >> 4) << 4) + (ks << 6)) ^ ((row & 7) << 4);
        bfr[ni] = *(const bf16x8*)((const char*)bT + row * 128 + cb);
      }
#pragma unroll
      for (int mi = 0; mi < 4; ++mi)
#pragma unroll
        for (int ni = 0; ni < 4; ++ni) {
          if (SWAP)
            acc[mi][ni] = __builtin_amdgcn_mfma_f32_16x16x32_bf16(
                bfr[ni], af[mi], acc[mi][ni], 0, 0, 0);
          else
            acc[mi][ni] = __builtin_amdgcn_mfma_f32_16x16x32_bf16(
                af[mi], bfr[ni], acc[mi][ni], 0, 0, 0);
        }
    }
    __syncthreads();
  }
}

// QKV GEMM: writes Q,K as [b*h][tok][d] bf16 and V transposed [b*h][d][tok].
__global__ __launch_bounds__(256) void gemm_qkv_kernel(
    const ushort_t* __restrict__ xb, const ushort_t* __restrict__ wT,
    const float* __restrict__ bias,
    ushort_t* __restrict__ Qb, ushort_t* __restrict__ Kb, ushort_t* __restrict__ Vt) {
  __shared__ __align__(16) ushort_t aT[128 * 64];
  __shared__ __align__(16) ushort_t bT[128 * 64];
  f32x4 acc[4][4];
  const int m0 = blockIdx.y * 128, n0 = blockIdx.x * 128;
  const int which = n0 >> 10;  // 0=q 1=k 2=v (128-tiles never straddle)

  const int t = threadIdx.x, l = t & 63;
  const int wr = t >> 7, wc = (t >> 6) & 1;

  if (which != 2) {
    gemm_tile_mainloop<false>(xb, wT, DIN, m0, n0, aT, bT, acc);
    // normal layout: m on (l>>4)*4+i, n on l&15
#pragma unroll
    for (int mi = 0; mi < 4; ++mi) {
#pragma unroll
      for (int ni = 0; ni < 4; ++ni) {
        const int n = n0 + wc * 64 + ni * 16 + (l & 15);
        const int h = (n >> 6) & 15, d = n & 63;
        const float bv = bias[n];
#pragma unroll
        for (int i = 0; i < 4; ++i) {
          const int m = m0 + wr * 64 + mi * 16 + ((l >> 4) << 2) + i;
          const int b = m >> 11, tok = m & 2047;
          const ushort_t val = f2bf(acc[mi][ni][i] + bv);
          const size_t bh = (size_t)((b << 4) + h);
          if (which == 0) Qb[(bh * NTOK + tok) * HDIM + d] = val;
          else            Kb[(bh * NTOK + tok) * HDIM + d] = val;
        }
      }
    }
  } else {
    gemm_tile_mainloop<true>(xb, wT, DIN, m0, n0, aT, bT, acc);
    // transposed layout: n on (l>>4)*4+i, m (token) on l&15 -> coalesced Vt
    const int b = m0 >> 11;                       // single batch per m-tile
    const int tok_base = (m0 & 2047) + wr * 64 + (l & 15);
    const int nd_base = (n0 - 2048) + wc * 64 + ((l >> 4) << 2);
#pragma unroll
    for (int mi = 0; mi < 4; ++mi) {
      const int tok = tok_base + mi * 16;
#pragma unroll
      for (int ni = 0; ni < 4; ++ni) {
#pragma unroll
        for (int i = 0; i < 4; ++i) {
          const int nd = nd_base + ni * 16 + i;
          const int h = nd >> 6, d = nd & 63;
          const float bv = bias[2048 + nd];
          Vt[(((size_t)((b << 4) + h) << 6) + d) * NTOK + tok] =
              f2bf(acc[mi][ni][i] + bv);
        }
      }
    }
  }
}

// proj GEMM: fp32 out + bias
__global__ __launch_bounds__(256) void gemm_proj_kernel(
    const ushort_t* __restrict__ ab, const ushort_t* __restrict__ wT,
    const float* __restrict__ bias, float* __restrict__ out) {
  __shared__ __align__(16) ushort_t aT[128 * 64];
  __shared__ __align__(16) ushort_t bT[128 * 64];
  f32x4 acc[4][4];
  const int m0 = blockIdx.y * 128, n0 = blockIdx.x * 128;
  gemm_tile_mainloop<false>(ab, wT, DIN, m0, n0, aT, bT, acc);

  const int t = threadIdx.x, l = t & 63;
  const int wr = t >> 7, wc = (t >> 6) & 1;
#pragma unroll
  for (int mi = 0; mi < 4; ++mi) {
#pragma unroll
    for (int ni = 0; ni < 4; ++ni) {
      const int n = n0 + wc * 64 + ni * 16 + (l & 15);
      const float bv = bias[n];
#pragma unroll
      for (int i = 0; i < 4; ++i) {
        const int m = m0 + wr * 64 + mi * 16 + ((l >> 4) << 2) + i;
        out[(size_t)m * 1024 + n] = acc[mi][ni][i] + bv;
      }
    }
  }
}

// column-mean of V over all 2048 rows, per (b,h,d): one wave per output.
__global__ __launch_bounds__(256) void vmean_kernel(
    const ushort_t* __restrict__ Vt, ushort_t* __restrict__ vmean) {
  const int row = blockIdx.x * 4 + (threadIdx.x >> 6);  // 0..2047 = bh*64+d
  const int l = threadIdx.x & 63;
  const ushort_t* src = Vt + (size_t)row * NTOK;
  float s = 0.f;
#pragma unroll
  for (int j = 0; j < 4; ++j) {
    u16x8 v = *(const u16x8*)(src + ((j << 6) + l) * 8);
#pragma unroll
    for (int k = 0; k < 8; ++k) s += bf2f(v[k]);
  }
#pragma unroll
  for (int d2 = 1; d2 < 64; d2 <<= 1) s += __shfl_xor(s, d2);
  if (l == 0) vmean[row] = f2bf(s * (1.0f / 2048.0f));
}

// ---------------------------------------------------------------------------
// flash attention, swapped-operand 32x32 MFMA.
// Block = 4 waves x 32 q-rows = 128 q. KV tile = 64, staged in LDS per BLOCK,
// double-buffered 2-phase pipeline: issue STAGE(t+1), compute(t), barrier.
// ---------------------------------------------------------------------------
__global__ __launch_bounds__(256) void attn_kernel(
    const ushort_t* __restrict__ Qb, const ushort_t* __restrict__ Kb,
    const ushort_t* __restrict__ Vt, const ushort_t* __restrict__ vmean,
    const int* __restrict__ validp, ushort_t* __restrict__ ob) {
  // buf p: K tile [64][64] at p*16384, V^T tile [64][64] at p*16384+8192.
  // epilogue ot (4 waves x 32x68 ushort = 17408B) overlays the same memory.
  __shared__ __align__(16) char smem_raw[32768];

  const int h = blockIdx.y, b = blockIdx.z;
  const int valid = validp[b];
  const int t = threadIdx.x, w = t >> 6, l = t & 63;
  const int lq = l & 31, hi = l >> 5;
  const int bq0 = blockIdx.x << 7;
  const int wq0 = bq0 + (w << 5);
  const size_t bh = (size_t)((b << 4) + h);
  const ushort_t* Qp = Qb + bh * (NTOK * HDIM);
  const ushort_t* Kp = Kb + bh * (NTOK * HDIM);
  const ushort_t* Vp = Vt + bh * (HDIM * NTOK);

  f32x16 oacc[2];
#pragma unroll
  for (int db = 0; db < 2; ++db)
#pragma unroll
    for (int r = 0; r < 16; ++r) oacc[db][r] = 0.f;
  float m_run = -INFINITY, lsum = 0.f;

  if (bq0 < valid) {
    const bool qvalid = (wq0 < valid);
    // hoisted Q B-fragments: q = wq0+lq, d = ks*16 + hi*8 + j
    bf16x8 qf[4];
    if (qvalid) {
      const ushort_t* qbase = Qp + (size_t)(wq0 + lq) * HDIM + (hi << 3);
#pragma unroll
      for (int ks = 0; ks < 4; ++ks) qf[ks] = *(const bf16x8*)(qbase + (ks << 4));
    }

    const int nt = (valid + 63) >> 6;

    // stage KV tile tt into buffer p (all 256 threads; coalesced gld_lds)
    auto STAGE = [&](int p, int kv0) {
      char* kdst = smem_raw + p * 16384;
      char* vdst = kdst + 8192;
#pragma unroll
      for (int c = 0; c < 2; ++c) {
        const int lin = c * 4096 + t * 16;
        const int row = lin >> 7;                        // 128B rows
        const int scb = (lin & 127) ^ ((row & 7) << 4);  // inverse-swizzle src
        const int ldso = c * 4096 + (w << 10);           // wave-uniform byte off
        gld_lds16(Kp + (size_t)(kv0 + row) * HDIM + (scb >> 1), kdst + ldso);
        gld_lds16(Vp + (size_t)row * NTOK + kv0 + (scb >> 1), vdst + ldso);
      }
    };

    STAGE(0, 0);
    __syncthreads();

    for (int tt = 0; tt < nt; ++tt) {
      const int p = tt & 1;
      const int kv0 = tt << 6;
      if (tt + 1 < nt) STAGE(p ^ 1, (tt + 1) << 6);

      if (qvalid) {
        const char* kbuf = smem_raw + p * 16384;
        const char* vbuf = kbuf + 8192;

        // K A-fragments from LDS: k-row = kb2*32+lq, elem col = ks*16+hi*8
        bf16x8 kf[2][4];
#pragma unroll
        for (int kb2 = 0; kb2 < 2; ++kb2) {
          const int row = (kb2 << 5) + lq;
          const int sw = (row & 7) << 4;
#pragma unroll
          for (int ks = 0; ks < 4; ++ks)
            kf[kb2][ks] = *(const bf16x8*)(kbuf + row * 128 + (((ks << 5) + (hi << 4)) ^ sw));
        }

        // S^T = K Q^T
        f32x16 st[2];
#pragma unroll
        for (int kb2 = 0; kb2 < 2; ++kb2)
#pragma unroll
          for (int r = 0; r < 16; ++r) st[kb2][r] = 0.f;
        __builtin_amdgcn_s_setprio(1);
#pragma unroll
        for (int ks = 0; ks < 4; ++ks) {
          st[0] = __builtin_amdgcn_mfma_f32_32x32x16_bf16(kf[0][ks], qf[ks], st[0], 0, 0, 0);
          st[1] = __builtin_amdgcn_mfma_f32_32x32x16_bf16(kf[1][ks], qf[ks], st[1], 0, 0, 0);
        }
        __builtin_amdgcn_s_setprio(0);

        // boundary-tile column mask
        if (kv0 + 64 > valid) {
#pragma unroll
          for (int kb2 = 0; kb2 < 2; ++kb2)
#pragma unroll
            for (int r = 0; r < 16; ++r) {
              const int k = kv0 + (kb2 << 5) + (r & 3) + ((r >> 2) << 3) + (hi << 2);
              if (k >= valid) st[kb2][r] = -1e30f;
            }
        }

        // row max (tree) + cross-half combine
        float pm;
        {
          float a8[8];
#pragma unroll
          for (int i = 0; i < 8; ++i)
            a8[i] = fmaxf(fmaxf(st[0][i], st[0][i + 8]), fmaxf(st[1][i], st[1][i + 8]));
          float b4[4];
#pragma unroll
          for (int i = 0; i < 4; ++i) b4[i] = fmaxf(a8[i], a8[i + 4]);
          pm = fmaxf(fmaxf(b4[0], b4[1]), fmaxf(b4[2], b4[3]));
        }
        pm = fmaxf(pm, __shfl_xor(pm, 32));

        // defer-max: rescale only when the running max actually grows (exact)
        if (__any(pm > m_run)) {
          const float mnew = fmaxf(m_run, pm);
          const float rs = exp2f((m_run - mnew) * SC);
          lsum *= rs;
#pragma unroll
          for (int db = 0; db < 2; ++db)
#pragma unroll
            for (int r = 0; r < 16; ++r) oacc[db][r] *= rs;
          m_run = mnew;
        }

        // P = exp2((S - m)*SC), sum
        const float mc = m_run * SC;
        float pp[2][16];
        float ts4[4] = {0.f, 0.f, 0.f, 0.f};
#pragma unroll
        for (int kb2 = 0; kb2 < 2; ++kb2)
#pragma unroll
          for (int r = 0; r < 16; ++r) {
            const float e = exp2f(fmaf(st[kb2][r], SC, -mc));
            pp[kb2][r] = e;
            ts4[r & 3] += e;
          }
        float tsum = (ts4[0] + ts4[1]) + (ts4[2] + ts4[3]);
        tsum += __shfl_xor(tsum, 32);
        lsum += tsum;

        // V^T A-fragments from LDS: d-row = db*32+lq, elem col = ks2*16+hi*8
        bf16x8 vf[2][4];
#pragma unroll
        for (int db = 0; db < 2; ++db) {
          const int row = (db << 5) + lq;
          const int sw = (row & 7) << 4;
#pragma unroll
          for (int ks2 = 0; ks2 < 4; ++ks2)
            vf[db][ks2] = *(const bf16x8*)(vbuf + row * 128 + (((ks2 << 5) + (hi << 4)) ^ sw));
        }

        // pack P to bf16 B-fragments (cvt_pk + cross-half shfl)
        bf16x8 pb[2][2];
#pragma unroll
        for (int kb2 = 0; kb2 < 2; ++kb2) {
          u32 c[8];
#pragma unroll
          for (int m2 = 0; m2 < 8; ++m2)
            c[m2] = cvt_pk_bf16(pp[kb2][2 * m2], pp[kb2][2 * m2 + 1]);
          const u32 x1 = (u32)__shfl_xor((int)(hi ? c[0] : c[2]), 32);
          const u32 x2 = (u32)__shfl_xor((int)(hi ? c[1] : c[3]), 32);
          const u32 x3 = (u32)__shfl_xor((int)(hi ? c[4] : c[6]), 32);
          const u32 x4 = (u32)__shfl_xor((int)(hi ? c[5] : c[7]), 32);
          u32x4 w0, w1;
          w0[0] = hi ? x1 : c[0];  w0[1] = hi ? x2 : c[1];
          w0[2] = hi ? c[2] : x1;  w0[3] = hi ? c[3] : x2;
          w1[0] = hi ? x3 : c[4];  w1[1] = hi ? x4 : c[5];
          w1[2] = hi ? c[6] : x3;  w1[3] = hi ? c[7] : x4;
          pb[kb2][0] = __builtin_bit_cast(bf16x8, w0);
          pb[kb2][1] = __builtin_bit_cast(bf16x8, w1);
        }

        // O^T += V^T P
        __builtin_amdgcn_s_setprio(1);
#pragma unroll
        for (int db = 0; db < 2; ++db)
#pragma unroll
          for (int kb2 = 0; kb2 < 2; ++kb2)
#pragma unroll
            for (int k2 = 0; k2 < 2; ++k2)
              oacc[db] = __builtin_amdgcn_mfma_f32_32x32x16_bf16(
                  vf[db][(kb2 << 1) + k2], pb[kb2][k2], oacc[db], 0, 0, 0);
        __builtin_amdgcn_s_setprio(0);
      }

      __syncthreads();   // drains STAGE vmcnt + protects both buffers
    }
  }

  // epilogue: normalize, transpose O^T via LDS (overlay), merge vmean, store.
  const float inv = (lsum > 0.f) ? 1.0f / lsum : 0.f;
  ushort_t* ot = (ushort_t*)smem_raw + w * (32 * 68);
#pragma unroll
  for (int db = 0; db < 2; ++db)
#pragma unroll
    for (int r = 0; r < 16; ++r) {
      const int d = (r & 3) + ((r >> 2) << 3) + (hi << 2) + (db << 5);
      ot[lq * 68 + d] = f2bf(oacc[db][r] * inv);
    }
  asm volatile("s_waitcnt lgkmcnt(0)" ::: "memory");
#pragma unroll
  for (int it = 0; it < 8; ++it) {
    const int c2 = it * 64 + l;        // 0..511 = 32 rows x 16 8B-chunks
    const int row = c2 >> 4;
    const int ch = c2 & 15;
    const uint2 vo = *(const uint2*)((const char*)ot + row * 136 + ch * 8);
    const uint2 vm = *(const uint2*)(vmean + (bh << 6) + ch * 4);
    const int grow = (blockIdx.x << 7) + (w << 5) + row;
    const uint2 sel = (grow < valid) ? vo : vm;
    *(uint2*)(ob + ((size_t)(b * NTOK) + grow) * 1024 + (h << 6) + ch * 4) = sel;
  }
}

// ---------------------------------------------------------------------------
extern "C" void kernel_launch(void* const* d_in, const int* in_sizes, int n_in,
                              void* d_out, int out_size, void* d_ws, size_t ws_size,
                              hipStream_t stream) {
  (void)in_sizes; (void)n_in; (void)out_size; (void)ws_size;
  const float* x      = (const float*)d_in[0];
  const int*   validp = (const int*)d_in[1];
  const float* W_qkv  = (const float*)d_in[2];
  const float* b_qkv  = (const float*)d_in[3];
  const float* W_proj = (const float*)d_in[4];
  const float* b_proj = (const float*)d_in[5];
  float* out = (float*)d_out;

  ushort_t* xb     = (ushort_t*)d_ws;        // 4194304 elems (x bf16)
  ushort_t* wqkvT  = xb + 4194304;           // 3145728  (W_qkv^T bf16 [3072][1024])
  ushort_t* wprojT = wqkvT + 3145728;        // 1048576  (W_proj^T bf16 [1024][1024])
  ushort_t* Qb     = wprojT + 1048576;       // 4194304  ([b*h][tok][d])
  ushort_t* Kb     = Qb + 4194304;           // 4194304
  ushort_t* Vt     = Kb + 4194304;           // 4194304  ([b*h][d][tok])
  ushort_t* ab     = Vt + 4194304;           // 4194304  (attn out bf16 [m][1024])
  ushort_t* vm     = ab + 4194304;           // 2048     (vmean bf16)

  prep_kernel<<<3072, 256, 0, stream>>>(x, xb, W_qkv, wqkvT, W_proj, wprojT);
  gemm_qkv_kernel<<<dim3(24, 32), 256, 0, stream>>>(xb, wqkvT, b_qkv, Qb, Kb, Vt);
  vmean_kernel<<<512, 256, 0, stream>>>(Vt, vm);
  attn_kernel<<<dim3(16, 16, 2), 256, 0, stream>>>(Qb, Kb, Vt, vm, validp, ab);
  gemm_proj_kernel<<<dim3(8, 32), 256, 0, stream>>>(ab, wprojT, b_proj, out);
}